// Round 2
// baseline (139.379 us; speedup 1.0000x reference)
//
#include <hip/hip_runtime.h>
#include <hip/hip_bf16.h>
#include <math.h>

// Problem constants (fixed by setup_inputs)
#define BB 2
#define HH 8
#define LQ 512
#define LK 512
#define DD 32

#define LOG2E 1.44269504088896f

static __device__ __forceinline__ float fast_rcp(float x) {
#if __has_builtin(__builtin_amdgcn_rcpf)
  return __builtin_amdgcn_rcpf(x);   // v_rcp_f32
#else
  return 1.0f / x;
#endif
}

static __device__ __forceinline__ float fast_exp2(float x) {
#if __has_builtin(__builtin_amdgcn_exp2f)
  return __builtin_amdgcn_exp2f(x);  // v_exp_f32
#else
  return __expf(x * 0.69314718056f);
#endif
}

// One wave (64 lanes) per output row (b,h,qi); each lane owns 8 k-columns.
__global__ __launch_bounds__(256) void gatv2_attn_kernel(
    const float* __restrict__ q, const float* __restrict__ k,
    const int* __restrict__ mask, const float* __restrict__ bias,
    const float* __restrict__ att, float* __restrict__ out) {
  const int lane = threadIdx.x & 63;
  const int wid = threadIdx.x >> 6;
  const int r = blockIdx.x * 4 + wid;      // row = ((b*H)+h)*LQ + qi, in [0, 8192)
  const int b = r >> 12;                    // / (H*LQ) = /4096
  const int h = (r >> 9) & (HH - 1);
  const int qi = r & (LQ - 1);

  const float* __restrict__ qrow = q + (size_t)r * DD;
  const float* __restrict__ kbase = k + ((size_t)(b * HH + h)) * (size_t)(LK * DD);
  const float* __restrict__ arow = att + h * DD;
  const float* __restrict__ brow = bias + (size_t)r * LK;
  const int* __restrict__ mrow = mask + ((size_t)(b * LQ + qi)) * LK;

  // Row-uniform q and attention vectors (broadcast loads; replicated in VGPRs)
  float qv[DD], av[DD];
#pragma unroll
  for (int d0 = 0; d0 < DD; d0 += 4) {
    const float4 qq = *(const float4*)(qrow + d0);
    const float4 aa = *(const float4*)(arow + d0);
    qv[d0 + 0] = qq.x; qv[d0 + 1] = qq.y; qv[d0 + 2] = qq.z; qv[d0 + 3] = qq.w;
    av[d0 + 0] = aa.x; av[d0 + 1] = aa.y; av[d0 + 2] = aa.z; av[d0 + 3] = aa.w;
  }

  float sc[8];
#pragma unroll
  for (int c = 0; c < 8; ++c) {
    const int kk = lane + 64 * c;
    const float* __restrict__ kr = kbase + (size_t)kk * DD;
    const float bval = brow[kk];           // coalesced
    const int mval = mrow[kk];             // coalesced
    float acc = 0.0f;
#pragma unroll
    for (int d0 = 0; d0 < DD; d0 += 4) {
      const float4 kv = *(const float4*)(kr + d0);
      const float kvf[4] = {kv.x, kv.y, kv.z, kv.w};
#pragma unroll
      for (int j = 0; j < 4; ++j) {
        const float t = qv[d0 + j] + kvf[j];
        const float e = fast_exp2(t * -LOG2E);       // e^{-t}
        const float sg = fast_rcp(1.0f + e);         // sigmoid(t)
        acc = fmaf(t * sg, av[d0 + j], acc);         // += silu(t)*a_d
      }
    }
    const float s = acc + bval;
    sc[c] = mval ? -INFINITY : s;
  }

  // Wave-wide softmax over the 512 columns (8 per lane)
  float m = sc[0];
#pragma unroll
  for (int c = 1; c < 8; ++c) m = fmaxf(m, sc[c]);
#pragma unroll
  for (int off = 32; off > 0; off >>= 1)
    m = fmaxf(m, __shfl_xor(m, off, 64));

  float sum = 0.0f;
#pragma unroll
  for (int c = 0; c < 8; ++c) {
    const float p = fast_exp2((sc[c] - m) * LOG2E);  // masked: exp2(-inf)=0
    sc[c] = p;
    sum += p;
  }
#pragma unroll
  for (int off = 32; off > 0; off >>= 1)
    sum += __shfl_xor(sum, off, 64);

  // Fully-masked row => m = -inf => reference nan_to_num gives exact 0.
  const bool dead = (m == -INFINITY);
  const float inv = dead ? 0.0f : fast_rcp(sum);     // sum >= 1 when alive

  float* __restrict__ orow = out + (size_t)r * LK;
#pragma unroll
  for (int c = 0; c < 8; ++c) {
    orow[lane + 64 * c] = dead ? 0.0f : sc[c] * inv; // coalesced stores
  }
}

extern "C" void kernel_launch(void* const* d_in, const int* in_sizes, int n_in,
                              void* d_out, int out_size, void* d_ws, size_t ws_size,
                              hipStream_t stream) {
  const float* q = (const float*)d_in[0];
  const float* k = (const float*)d_in[1];
  // d_in[2] = scale, unused by the reference module
  const int* mask = (const int*)d_in[3];
  const float* bias = (const float*)d_in[4];
  const float* att = (const float*)d_in[5];
  float* out = (float*)d_out;

  const int rows = BB * HH * LQ;            // 8192 rows
  dim3 grid(rows / 4), block(256);
  gatv2_attn_kernel<<<grid, block, 0, stream>>>(q, k, mask, bias, att, out);
}